// Round 1
// baseline (618.489 us; speedup 1.0000x reference)
//
#include <hip/hip_runtime.h>
#include <math.h>

#define TM 32

__device__ __forceinline__ float sigmoidf_(float x){ return 1.0f/(1.0f + __expf(-x)); }

// ---------- tiny precompute: x-part of layer1 + bias ----------
__global__ void k_pre(const float* __restrict__ x,
                      const float* __restrict__ Wa1, const float* __restrict__ ba1,
                      const float* __restrict__ Wg1, const float* __restrict__ bg1,
                      float* __restrict__ xa, float* __restrict__ xg){
  __shared__ float sx[64];
  int tid = threadIdx.x;
  if (tid < 64) sx[tid] = x[tid];
  __syncthreads();
  if (tid < 128){
    const float* w = Wa1 + tid*192;
    float s = ba1[tid];
    #pragma unroll
    for (int i=0;i<64;i++) s += w[i]*sx[i];
    xa[tid] = s;
  } else {
    int j = tid-128;
    const float* w = Wg1 + j*192;
    float s = bg1[j];
    #pragma unroll
    for (int i=0;i<64;i++) s += w[i]*sx[i];
    xg[j] = s;
  }
}

// ---------- transpose weights into [k][n] so lane loads coalesce ----------
__global__ void k_transpose(const float* __restrict__ Wa1, const float* __restrict__ Wg1,
                            const float* __restrict__ Wa2, const float* __restrict__ Wg2,
                            const float* __restrict__ Wih, const float* __restrict__ Whh,
                            float* __restrict__ W1T, float* __restrict__ W2T,
                            float* __restrict__ WihT, float* __restrict__ WhhT){
  int stride = gridDim.x*blockDim.x;
  int t0 = blockIdx.x*blockDim.x + threadIdx.x;
  for (int i=t0; i<128*256; i+=stride){ int k=i>>8, nn=i&255;
    W1T[i] = (nn<128) ? Wa1[nn*192+64+k] : Wg1[(nn-128)*192+64+k]; }
  for (int i=t0; i<128*128; i+=stride){ int k=i>>7, nn=i&127;
    W2T[i] = (nn<64) ? Wa2[nn*128+k] : Wg2[(nn-64)*128+k]; }
  for (int i=t0; i<65*384; i+=stride){ int k=i/384, nn=i-k*384;
    WihT[i] = Wih[nn*65+k]; }
  for (int i=t0; i<128*384; i+=stride){ int k=i/384, nn=i-k*384;
    WhhT[i] = Whh[nn*128+k]; }
}

__global__ void k_mark(const int* __restrict__ alive, unsigned* __restrict__ flags, int n){
  int i = blockIdx.x*blockDim.x + threadIdx.x;
  if (i < n) flags[alive[i]] = 1u;
}

// ---------- main per-cell kernel: 32 cells / block ----------
__global__ __launch_bounds__(256,2) void k_main(
    const float* __restrict__ hiddens, const int* __restrict__ alive,
    const float* __restrict__ W1T, const float* __restrict__ W2T,
    const float* __restrict__ WihT, const float* __restrict__ WhhT,
    const float* __restrict__ xa, const float* __restrict__ xg,
    const float* __restrict__ ba2, const float* __restrict__ bg2,
    const float* __restrict__ bih, const float* __restrict__ bhh,
    float* __restrict__ nh, float* __restrict__ facsum,
    float* __restrict__ recs, unsigned* __restrict__ tmax_u, float* __restrict__ tsum,
    int n, int fs, int nffs)
{
  __shared__ float sH[TM][128];     // gathered h
  __shared__ float sVG[TM][256];    // v1 (relu layer1) then gate r|z
  __shared__ float sAI[TM][128];    // a|g (layer2) then new_h
  __shared__ float sOut[TM][68];    // [0..63]=out, [64]=tension
  __shared__ float sNum[4][64];
  __shared__ float sMb, sSb;
  __shared__ int   sIdx[TM];

  int tid = threadIdx.x;
  int base = blockIdx.x * TM;
  int nvalid = n - base; if (nvalid > TM) nvalid = TM;

  if (tid < TM) sIdx[tid] = alive[base + ((tid < nvalid) ? tid : 0)];
  __syncthreads();
  for (int e = tid; e < TM*128; e += 256){
    int m = e >> 7, j = e & 127;
    sH[m][j] = hiddens[(size_t)sIdx[m]*128 + j];
  }
  __syncthreads();

  // ---- layer1: v1 = relu([x,h]@W1^T + b); 256 cols (a:0-127, g:128-255)
  {
    int nt = tid & 63, mt = tid >> 6;
    int ncol = nt*4, m0 = mt*8;
    float4 acc[8];
    #pragma unroll
    for (int m=0;m<8;m++){ acc[m].x=0.f; acc[m].y=0.f; acc[m].z=0.f; acc[m].w=0.f; }
    for (int k=0;k<128;k++){
      float4 w = *(const float4*)(W1T + k*256 + ncol);
      #pragma unroll
      for (int m=0;m<8;m++){
        float h = sH[m0+m][k];
        acc[m].x += w.x*h; acc[m].y += w.y*h; acc[m].z += w.z*h; acc[m].w += w.w*h;
      }
    }
    float4 bias = (ncol < 128) ? *(const float4*)(xa + ncol)
                               : *(const float4*)(xg + ncol - 128);
    #pragma unroll
    for (int m=0;m<8;m++){
      float4 v;
      v.x = fmaxf(acc[m].x + bias.x, 0.f);
      v.y = fmaxf(acc[m].y + bias.y, 0.f);
      v.z = fmaxf(acc[m].z + bias.z, 0.f);
      v.w = fmaxf(acc[m].w + bias.w, 0.f);
      *(float4*)(&sVG[m0+m][ncol]) = v;
    }
  }
  __syncthreads();

  // ---- layer2: a|g; 128 cols (a:0-63, g:64-127)
  {
    int nt = tid & 31, mt = tid >> 5;
    int ncol = nt*4, m0 = mt*4;
    int koff = (nt < 16) ? 0 : 128;
    float4 acc[4];
    #pragma unroll
    for (int m=0;m<4;m++){ acc[m].x=0.f; acc[m].y=0.f; acc[m].z=0.f; acc[m].w=0.f; }
    for (int k=0;k<128;k++){
      float4 w = *(const float4*)(W2T + k*128 + ncol);
      #pragma unroll
      for (int m=0;m<4;m++){
        float v = sVG[m0+m][koff + k];
        acc[m].x += w.x*v; acc[m].y += w.y*v; acc[m].z += w.z*v; acc[m].w += w.w*v;
      }
    }
    float4 bias = (ncol < 64) ? *(const float4*)(ba2 + ncol)
                              : *(const float4*)(bg2 + ncol - 64);
    #pragma unroll
    for (int m=0;m<4;m++){
      float4 v;
      v.x = acc[m].x + bias.x; v.y = acc[m].y + bias.y;
      v.z = acc[m].z + bias.z; v.w = acc[m].w + bias.w;
      *(float4*)(&sAI[m0+m][ncol]) = v;
    }
  }
  __syncthreads();

  // ---- out = a - g
  {
    int c4 = tid & 15, mg = tid >> 4;
    #pragma unroll
    for (int mm=0;mm<2;mm++){
      int m = mg*2+mm;
      float4 a = *(const float4*)(&sAI[m][c4*4]);
      float4 g = *(const float4*)(&sAI[m][64+c4*4]);
      float4 o; o.x=a.x-g.x; o.y=a.y-g.y; o.z=a.z-g.z; o.w=a.w-g.w;
      *(float4*)(&sOut[m][c4*4]) = o;
    }
  }
  __syncthreads();

  // ---- tension + block softmax stats
  if (tid < 32){
    int m = tid;
    float s = 0.f;
    #pragma unroll
    for (int c4=0;c4<16;c4++){
      float4 o = *(const float4*)(&sOut[m][c4*4]);
      s += o.x*o.x + o.y*o.y + o.z*o.z + o.w*o.w;
    }
    float t = s * (1.0f/64.0f);
    sOut[m][64] = t;
    bool valid = (m < nvalid);
    float mx = valid ? t : -INFINITY;
    #pragma unroll
    for (int off=16; off>0; off>>=1) mx = fmaxf(mx, __shfl_xor(mx, off, 32));
    float e  = valid ? __expf(t - mx) : 0.f;
    float st = valid ? t : 0.f;
    float se = e;
    #pragma unroll
    for (int off=16; off>0; off>>=1){ se += __shfl_xor(se, off, 32); st += __shfl_xor(st, off, 32); }
    if (tid == 0){
      sMb = mx; sSb = se;
      atomicMax(tmax_u, __float_as_uint(mx));   // t >= 0 -> uint order == float order
      atomicAdd(tsum, st);
    }
  }
  __syncthreads();

  // ---- block-local softmax numerator
  {
    int c = tid & 63, mg = tid >> 6;
    float Mb = sMb;
    float acc = 0.f;
    #pragma unroll
    for (int mm=0;mm<8;mm++){
      int m = mg*8+mm;
      if (m < nvalid) acc += __expf(sOut[m][64] - Mb) * sOut[m][c];
    }
    sNum[mg][c] = acc;
  }
  __syncthreads();
  if (tid < 64){
    float nb = sNum[0][tid]+sNum[1][tid]+sNum[2][tid]+sNum[3][tid];
    float* rec = recs + (size_t)blockIdx.x*66;
    rec[2+tid] = nb;
    if (tid == 0){ rec[0] = sMb; rec[1] = sSb; }
  }

  // ---- GRU r|z gates (cols 0..255): gh(K=128) + gi(K=65)
  {
    int nt = tid & 63, mt = tid >> 6;
    int ncol = nt*4, m0 = mt*8;
    float4 bi = *(const float4*)(bih + ncol);
    float4 bh = *(const float4*)(bhh + ncol);
    float4 acc[8];
    #pragma unroll
    for (int m=0;m<8;m++){ acc[m].x=bi.x+bh.x; acc[m].y=bi.y+bh.y; acc[m].z=bi.z+bh.z; acc[m].w=bi.w+bh.w; }
    for (int k=0;k<128;k++){
      float4 w = *(const float4*)(WhhT + k*384 + ncol);
      #pragma unroll
      for (int m=0;m<8;m++){
        float h = sH[m0+m][k];
        acc[m].x += w.x*h; acc[m].y += w.y*h; acc[m].z += w.z*h; acc[m].w += w.w*h;
      }
    }
    for (int k=0;k<65;k++){
      float4 w = *(const float4*)(WihT + k*384 + ncol);
      #pragma unroll
      for (int m=0;m<8;m++){
        float o = sOut[m0+m][k];
        acc[m].x += w.x*o; acc[m].y += w.y*o; acc[m].z += w.z*o; acc[m].w += w.w*o;
      }
    }
    #pragma unroll
    for (int m=0;m<8;m++) *(float4*)(&sVG[m0+m][ncol]) = acc[m];
  }

  // ---- GRU candidate: inn (K=65) and hn (K=128) kept separate in regs
  {
    int nt = tid & 31, mt = tid >> 5;
    int j0 = nt*4, m0 = mt*4;
    float4 bi = *(const float4*)(bih + 256 + j0);
    float4 bh = *(const float4*)(bhh + 256 + j0);
    float4 aI[4], aH[4];
    #pragma unroll
    for (int m=0;m<4;m++){ aI[m]=bi; aH[m]=bh; }
    for (int k=0;k<65;k++){
      float4 w = *(const float4*)(WihT + k*384 + 256 + j0);
      #pragma unroll
      for (int m=0;m<4;m++){
        float o = sOut[m0+m][k];
        aI[m].x += w.x*o; aI[m].y += w.y*o; aI[m].z += w.z*o; aI[m].w += w.w*o;
      }
    }
    for (int k=0;k<128;k++){
      float4 w = *(const float4*)(WhhT + k*384 + 256 + j0);
      #pragma unroll
      for (int m=0;m<4;m++){
        float h = sH[m0+m][k];
        aH[m].x += w.x*h; aH[m].y += w.y*h; aH[m].z += w.z*h; aH[m].w += w.w*h;
      }
    }
    __syncthreads();   // r|z gate writes to sVG complete
    #pragma unroll
    for (int mm=0;mm<4;mm++){
      int m = m0+mm;
      float4 rv = *(const float4*)(&sVG[m][j0]);
      float4 zv = *(const float4*)(&sVG[m][128+j0]);
      float4 hv = *(const float4*)(&sH[m][j0]);
      float4 o;
      { float r=sigmoidf_(rv.x), z=sigmoidf_(zv.x);
        float nv=tanhf(aI[mm].x + r*aH[mm].x); o.x=(1.f-z)*nv + z*hv.x; }
      { float r=sigmoidf_(rv.y), z=sigmoidf_(zv.y);
        float nv=tanhf(aI[mm].y + r*aH[mm].y); o.y=(1.f-z)*nv + z*hv.y; }
      { float r=sigmoidf_(rv.z), z=sigmoidf_(zv.z);
        float nv=tanhf(aI[mm].z + r*aH[mm].z); o.z=(1.f-z)*nv + z*hv.z; }
      { float r=sigmoidf_(rv.w), z=sigmoidf_(zv.w);
        float nv=tanhf(aI[mm].w + r*aH[mm].w); o.w=(1.f-z)*nv + z*hv.w; }
      *(float4*)(&sAI[m][j0]) = o;   // sAI now holds new_h (pre-faction)
    }
  }
  __syncthreads();

  // ---- coalesced scatter of pre-faction new_h + faction column sums
  for (int e = tid; e < TM*128; e += 256){
    int m = e >> 7, j = e & 127;
    if (m < nvalid) nh[(size_t)sIdx[m]*128 + j] = sAI[m][j];
  }
  if (tid < 128){
    int j = tid;
    float s = 0.f; int fprev = -1;
    for (int m=0; m<nvalid; m++){
      int gi2 = base + m;
      int f = (gi2 < nffs) ? (gi2 / fs) : -1;
      if (f != fprev){
        if (fprev >= 0) atomicAdd(&facsum[fprev*128+j], s);
        s = 0.f; fprev = f;
      }
      if (f >= 0) s += sAI[m][j];
    }
    if (fprev >= 0) atomicAdd(&facsum[fprev*128+j], s);
  }
}

// ---------- combine per-block softmax records ----------
__global__ void k_comb1(const float* __restrict__ recs, int nrec,
                        const unsigned* __restrict__ tmax_u,
                        float* __restrict__ num, float* __restrict__ S){
  int tid = threadIdx.x;
  int c = tid & 63, rg = tid >> 6;
  float M = __uint_as_float(*tmax_u);
  float acc = 0.f, sacc = 0.f;
  for (int r = blockIdx.x*4 + rg; r < nrec; r += gridDim.x*4){
    const float* rec = recs + (size_t)r*66;
    float e = __expf(rec[0] - M);
    acc += e * rec[2+c];
    if (c == 0) sacc += e * rec[1];
  }
  __shared__ float sn[4][64];
  __shared__ float ss[4];
  sn[rg][c] = acc;
  if (c == 0) ss[rg] = sacc;
  __syncthreads();
  if (tid < 64) atomicAdd(&num[tid], sn[0][tid]+sn[1][tid]+sn[2][tid]+sn[3][tid]);
  if (tid == 64) atomicAdd(S, ss[0]+ss[1]+ss[2]+ss[3]);
}

// ---------- finalize combined / mean_tension / faction means ----------
__global__ void k_final(const float* __restrict__ num, const float* __restrict__ S,
                        const float* __restrict__ tsum, const float* __restrict__ facsum,
                        float* __restrict__ out, float* __restrict__ go, float* __restrict__ fmn,
                        int n, int n_f, int fs){
  int tid = threadIdx.x;
  if (tid < 64) out[tid] = num[tid] / *S;
  else if (tid == 64) out[64] = *tsum / (float)n;
  if (tid >= 128 && n_f >= 2){
    int j = tid - 128;
    float s = 0.f;
    for (int f=0; f<n_f; f++){
      float v = facsum[f*128+j];
      s += v;
      fmn[f*128+j] = v / (float)fs;
    }
    go[j] = s / (float)(n_f*fs);
  }
}

// ---------- copy non-alive rows into new_hiddens ----------
__global__ void k_copy(const float* __restrict__ hid, const unsigned* __restrict__ flags,
                       float* __restrict__ nh, int total4){
  int stride = gridDim.x*blockDim.x;
  for (int i = blockIdx.x*blockDim.x + threadIdx.x; i < total4; i += stride){
    int e = i*4;
    if (!flags[e >> 7]){
      float4 v = *(const float4*)(hid + e);
      nh[e] = v.x; nh[e+1] = v.y; nh[e+2] = v.z; nh[e+3] = v.w;   // nh is only 4B-aligned (d_out+65)
    }
  }
}

// ---------- in-place faction sync + debate on alive rows ----------
__global__ void k_faction(const int* __restrict__ alive, const float* __restrict__ fmn,
                          const float* __restrict__ go, const int* __restrict__ step_p,
                          float* __restrict__ nh, int nffs, int fs, int dc){
  int stride = gridDim.x*blockDim.x;
  int total = nffs*128;
  bool debate = (*step_p > 5);
  for (int e = blockIdx.x*blockDim.x + threadIdx.x; e < total; e += stride){
    int i = e >> 7, j = e & 127;
    int a = alive[i];
    size_t off = (size_t)a*128 + j;
    float v = nh[off];
    int f = i / fs;
    v = 0.85f*v + 0.15f*fmn[f*128+j];
    if (debate && (i - f*fs) < dc) v = 0.85f*v + 0.15f*go[j];
    nh[off] = v;
  }
}

extern "C" void kernel_launch(void* const* d_in, const int* in_sizes, int n_in,
                              void* d_out, int out_size, void* d_ws, size_t ws_size,
                              hipStream_t stream){
  const float* x    = (const float*)d_in[0];
  const float* hid  = (const float*)d_in[1];
  const float* Wa1  = (const float*)d_in[2];
  const float* ba1  = (const float*)d_in[3];
  const float* Wa2  = (const float*)d_in[4];
  const float* ba2  = (const float*)d_in[5];
  const float* Wg1  = (const float*)d_in[6];
  const float* bg1  = (const float*)d_in[7];
  const float* Wg2  = (const float*)d_in[8];
  const float* bg2  = (const float*)d_in[9];
  const float* Wih  = (const float*)d_in[10];
  const float* Whh  = (const float*)d_in[11];
  const float* bih  = (const float*)d_in[12];
  const float* bhh  = (const float*)d_in[13];
  const int*   alive= (const int*)d_in[14];
  const int*   step = (const int*)d_in[15];

  int n = in_sizes[14];
  int n_cells = in_sizes[1] / 128;
  int n_f = (n/2 < 8) ? n/2 : 8;
  int fs   = (n_f >= 2) ? n / n_f : 0;
  int nffs = (n_f >= 2) ? n_f * fs : 0;
  int dc   = (fs/4 > 1) ? fs/4 : 1;
  int nblocks = (n + TM - 1) / TM;

  float* out = (float*)d_out;
  float* nh  = out + 65;          // new_hiddens region (4B-aligned only!)
  float* ws  = (float*)d_ws;

  float* xa    = ws + 0;          // 128
  float* xg    = ws + 128;        // 128
  float* facs  = ws + 256;        // 1024
  float* num   = ws + 1280;       // 64
  float* Ssum  = ws + 1344;       // 1
  float* tsum  = ws + 1345;       // 1
  unsigned* tmax_u = (unsigned*)(ws + 1346);  // 1 (+pad)
  float* go    = ws + 1348;       // 128
  float* fmn   = ws + 1476;       // 1024
  float* W1T   = ws + 2500;       // 128*256
  float* W2T   = ws + 35268;      // 128*128
  float* WihT  = ws + 51652;      // 65*384
  float* WhhT  = ws + 76612;      // 128*384
  float* recs  = ws + 125764;     // nblocks*66
  unsigned* flags = (unsigned*)(ws + 125764 + ((nblocks*66 + 3) & ~3));

  // zero atomic accumulators (facs..tmax inclusive) and flags
  hipMemsetAsync(ws + 256, 0, 1092*sizeof(float), stream);
  hipMemsetAsync(flags, 0, (size_t)n_cells*sizeof(unsigned), stream);

  k_pre<<<1,256,0,stream>>>(x, Wa1, ba1, Wg1, bg1, xa, xg);
  k_transpose<<<208,256,0,stream>>>(Wa1, Wg1, Wa2, Wg2, Wih, Whh, W1T, W2T, WihT, WhhT);
  k_mark<<<(n+255)/256,256,0,stream>>>(alive, flags, n);
  k_main<<<nblocks,256,0,stream>>>(hid, alive, W1T, W2T, WihT, WhhT, xa, xg,
                                   ba2, bg2, bih, bhh, nh, facs, recs, tmax_u, tsum,
                                   n, fs, nffs);
  k_comb1<<<64,256,0,stream>>>(recs, nblocks, tmax_u, num, Ssum);
  k_final<<<1,256,0,stream>>>(num, Ssum, tsum, facs, out, go, fmn, n, n_f, fs);
  k_copy<<<2048,256,0,stream>>>(hid, flags, nh, n_cells*128/4);
  if (n_f >= 2)
    k_faction<<<2048,256,0,stream>>>(alive, fmn, go, step, nh, nffs, fs, dc);
}

// Round 2
// 257.720 us; speedup vs baseline: 2.3999x; 2.3999x over previous
//
#include <hip/hip_runtime.h>
#include <math.h>

#define TMC 64   // cells per k_main block

typedef __attribute__((ext_vector_type(4))) float f32x4;
typedef __attribute__((ext_vector_type(8))) short bf16x8;

#define MFMA16(a,b,c) __builtin_amdgcn_mfma_f32_16x16x32_bf16((a),(b),(c),0,0,0)

__device__ __forceinline__ float sigmoidf_(float x){ return 1.0f/(1.0f + __expf(-x)); }

__device__ __forceinline__ unsigned short f2bf(float f){
  unsigned u = __float_as_uint(f);
  unsigned r = (u + 0x7FFFu + ((u>>16)&1u)) >> 16;
  return (unsigned short)r;
}
__device__ __forceinline__ unsigned pack2(float a, float b){
  return (unsigned)f2bf(a) | ((unsigned)f2bf(b)<<16);
}
__device__ __forceinline__ float bf2f(unsigned short u){ return __uint_as_float(((unsigned)u)<<16); }

__device__ __forceinline__ bf16x8 lds_ld8(const ushort* base, int byte){
  return *reinterpret_cast<const bf16x8*>(reinterpret_cast<const char*>(base) + byte);
}

// ---------- precompute: x-part of layer1 + combined biases (f32) ----------
__global__ void k_pre(const float* __restrict__ x,
                      const float* __restrict__ Wa1, const float* __restrict__ ba1,
                      const float* __restrict__ Wg1, const float* __restrict__ bg1,
                      const float* __restrict__ ba2, const float* __restrict__ bg2,
                      const float* __restrict__ bih, const float* __restrict__ bhh,
                      float* __restrict__ xab, float* __restrict__ b2d, float* __restrict__ brz){
  __shared__ float sx[64];
  int tid = threadIdx.x;
  if (tid < 64) sx[tid] = x[tid];
  __syncthreads();
  if (tid < 128){
    const float* w = Wa1 + tid*192;
    float s = ba1[tid];
    #pragma unroll
    for (int i=0;i<64;i++) s += w[i]*sx[i];
    xab[tid] = s;
  } else {
    int j = tid-128;
    const float* w = Wg1 + j*192;
    float s = bg1[j];
    #pragma unroll
    for (int i=0;i<64;i++) s += w[i]*sx[i];
    xab[tid] = s;
  }
  if (tid < 64) b2d[tid] = ba2[tid] - bg2[tid];
  brz[tid] = bih[tid] + bhh[tid];
}

// ---------- pack weights to bf16 [N][K] ----------
__global__ void k_pack(const float* __restrict__ Wa1, const float* __restrict__ Wg1,
                       const float* __restrict__ Wa2, const float* __restrict__ Wg2,
                       const float* __restrict__ Wih, const float* __restrict__ Whh,
                       ushort* __restrict__ W1p, ushort* __restrict__ W2p,
                       ushort* __restrict__ Wgi, ushort* __restrict__ Whhb){
  int stride = gridDim.x*blockDim.x;
  int t0 = blockIdx.x*blockDim.x + threadIdx.x;
  for (int i=t0; i<256*128; i+=stride){ int r=i>>7, k=i&127;
    float v = (r<128) ? Wa1[r*192+64+k] : Wg1[(r-128)*192+64+k];
    W1p[i] = f2bf(v); }
  for (int i=t0; i<128*128; i+=stride){ int r=i>>7, k=i&127;
    float v = (r<64) ? Wa2[r*128+k] : Wg2[(r-64)*128+k];
    W2p[i] = f2bf(v); }
  for (int i=t0; i<384*96; i+=stride){ int r=i/96, k=i-r*96;
    Wgi[i] = (k<65) ? f2bf(Wih[r*65+k]) : (ushort)0; }
  for (int i=t0; i<384*128; i+=stride){ Whhb[i] = f2bf(Whh[i]); }
}

__global__ void k_mark(const int* __restrict__ alive, unsigned* __restrict__ flags, int n){
  int i = blockIdx.x*blockDim.x + threadIdx.x;
  if (i < n) flags[alive[i]] = 1u;
}

// GRU gate GEMM accumulate: acc[4 M-tiles][2 N-tiles]
template<bool DOMEM, bool DOH>
__device__ __forceinline__ void gate_accum(f32x4 (&acc)[4][2],
    const ushort* sMIH, const ushort* sH,
    const ushort* __restrict__ Wgi, const ushort* __restrict__ Whhb,
    int rowbase, int jo3, int l15, int lg)
{
  if (DOMEM){
    #pragma unroll
    for (int ks=0; ks<3; ks++){
      bf16x8 a[4], b[2];
      #pragma unroll
      for (int tm=0; tm<4; tm++){
        int row = tm*16 + l15;
        a[tm] = lds_ld8(sMIH, (row*192 + ks*64 + lg*16) ^ ((row&7)<<4));
      }
      #pragma unroll
      for (int tn=0; tn<2; tn++)
        b[tn] = *(const bf16x8*)(Wgi + (size_t)(rowbase + jo3 + tn*16 + l15)*96 + ks*32 + lg*8);
      #pragma unroll
      for (int tm=0; tm<4; tm++)
        #pragma unroll
        for (int tn=0; tn<2; tn++)
          acc[tm][tn] = MFMA16(a[tm], b[tn], acc[tm][tn]);
    }
  }
  if (DOH){
    #pragma unroll
    for (int ks=0; ks<4; ks++){
      bf16x8 a[4], b[2];
      #pragma unroll
      for (int tm=0; tm<4; tm++){
        int row = tm*16 + l15;
        a[tm] = lds_ld8(sH, (row*256 + ks*64 + lg*16) ^ ((row&7)<<4));
      }
      #pragma unroll
      for (int tn=0; tn<2; tn++)
        b[tn] = *(const bf16x8*)(Whhb + (size_t)(rowbase + jo3 + tn*16 + l15)*128 + ks*32 + lg*8);
      #pragma unroll
      for (int tm=0; tm<4; tm++)
        #pragma unroll
        for (int tn=0; tn<2; tn++)
          acc[tm][tn] = MFMA16(a[tm], b[tn], acc[tm][tn]);
    }
  }
}

// ---------- main MFMA kernel: 64 cells / block, 4 waves ----------
__global__ __launch_bounds__(256,2) void k_main(
    const float* __restrict__ hiddens, const int* __restrict__ alive,
    const ushort* __restrict__ W1p, const ushort* __restrict__ W2p,
    const ushort* __restrict__ Wgi, const ushort* __restrict__ Whhb,
    const float* __restrict__ xab, const float* __restrict__ b2d,
    const float* __restrict__ brz,
    const float* __restrict__ bih, const float* __restrict__ bhh,
    float* __restrict__ nh, float* __restrict__ facsum,
    float* __restrict__ recs, unsigned* __restrict__ tmax_u, float* __restrict__ tsum,
    int n, int fs, int nffs)
{
  __shared__ ushort sH[64*128];                 // 16 KB  (bf16, swizzled, stride 256B)
  __shared__ __align__(16) char arena[64*256*2];// 32 KB  sV1 (bf16, stride 512B) then sNH (f32 [64][128])
  __shared__ ushort sMIH[64*96];                // 12 KB  (bf16, swizzled, stride 192B)
  __shared__ int   sIdx[TMC];
  __shared__ float sE[64];

  ushort* sV1 = (ushort*)arena;
  float*  sNH = (float*)arena;

  int tid = threadIdx.x;
  int lane = tid & 63;
  int w = tid >> 6;
  int l15 = lane & 15;
  int lg  = lane >> 4;

  int base = blockIdx.x * TMC;
  int nvalid = n - base; if (nvalid > TMC) nvalid = TMC;

  if (tid < TMC){
    int t2 = tid < nvalid ? tid : (nvalid-1);
    sIdx[tid] = alive[base + t2];
  }
  __syncthreads();

  // ---- stage h -> bf16 LDS (swizzled); zero sMIH k-pad cols 64..95
  {
    int m = tid >> 2, c0 = (tid & 3) * 32;
    const float* src = hiddens + (size_t)sIdx[m]*128 + c0;
    #pragma unroll
    for (int j=0; j<32; j+=8){
      float4 v0 = *(const float4*)(src + j);
      float4 v1 = *(const float4*)(src + j + 4);
      uint4 pk;
      pk.x = pack2(v0.x, v0.y); pk.y = pack2(v0.z, v0.w);
      pk.z = pack2(v1.x, v1.y); pk.w = pack2(v1.z, v1.w);
      int byte = (m*256 + (c0 + j)*2) ^ ((m&7)<<4);
      *reinterpret_cast<uint4*>(reinterpret_cast<char*>(sH) + byte) = pk;
    }
    int cz = 64 + (tid & 3)*8;
    int byte = (m*192 + cz*2) ^ ((m&7)<<4);
    *reinterpret_cast<uint4*>(reinterpret_cast<char*>(sMIH) + byte) = make_uint4(0,0,0,0);
  }
  __syncthreads();

  // ---- GEMM1: v1 = relu(h @ W1h^T + xab); wave w -> cols [w*64, w*64+64)
  {
    int c0 = w*64;
    f32x4 acc[4][4];
    #pragma unroll
    for (int tm=0;tm<4;tm++)
      #pragma unroll
      for (int tn=0;tn<4;tn++) acc[tm][tn] = (f32x4)0.f;
    #pragma unroll
    for (int ks=0; ks<4; ks++){
      bf16x8 a[4], b[4];
      #pragma unroll
      for (int tm=0;tm<4;tm++){
        int row = tm*16 + l15;
        a[tm] = lds_ld8(sH, (row*256 + ks*64 + lg*16) ^ ((row&7)<<4));
      }
      #pragma unroll
      for (int tn=0;tn<4;tn++)
        b[tn] = *(const bf16x8*)(W1p + (size_t)(c0 + tn*16 + l15)*128 + ks*32 + lg*8);
      #pragma unroll
      for (int tm=0;tm<4;tm++)
        #pragma unroll
        for (int tn=0;tn<4;tn++)
          acc[tm][tn] = MFMA16(a[tm], b[tn], acc[tm][tn]);
    }
    #pragma unroll
    for (int tn=0;tn<4;tn++){
      int col = c0 + tn*16 + l15;
      float bias = xab[col];
      #pragma unroll
      for (int tm=0;tm<4;tm++){
        #pragma unroll
        for (int r=0;r<4;r++){
          int row = tm*16 + lg*4 + r;
          float v = fmaxf(acc[tm][tn][r] + bias, 0.f);
          int byte = (row*512 + col*2) ^ ((row&7)<<4);
          *(ushort*)((char*)sV1 + byte) = f2bf(v);
        }
      }
    }
  }
  __syncthreads();

  // ---- GEMM2: out = a - g; wave w -> out cols [w*16, w*16+16)
  int jo2 = w*16;
  float outv[4][4];
  {
    f32x4 accA[4], accG[4];
    #pragma unroll
    for (int tm=0;tm<4;tm++){ accA[tm]=(f32x4)0.f; accG[tm]=(f32x4)0.f; }
    #pragma unroll
    for (int ks=0; ks<4; ks++){
      bf16x8 aA[4], aG[4], bA, bG;
      #pragma unroll
      for (int tm=0;tm<4;tm++){
        int row = tm*16 + l15;
        aA[tm] = lds_ld8(sV1, (row*512 + ks*64 + lg*16) ^ ((row&7)<<4));
        aG[tm] = lds_ld8(sV1, (row*512 + 256 + ks*64 + lg*16) ^ ((row&7)<<4));
      }
      bA = *(const bf16x8*)(W2p + (size_t)(jo2 + l15)*128 + ks*32 + lg*8);
      bG = *(const bf16x8*)(W2p + (size_t)(64 + jo2 + l15)*128 + ks*32 + lg*8);
      #pragma unroll
      for (int tm=0;tm<4;tm++){
        accA[tm] = MFMA16(aA[tm], bA, accA[tm]);
        accG[tm] = MFMA16(aG[tm], bG, accG[tm]);
      }
    }
    int col = jo2 + l15;
    float bias = b2d[col];
    #pragma unroll
    for (int tm=0;tm<4;tm++){
      #pragma unroll
      for (int r=0;r<4;r++){
        float o = accA[tm][r] - accG[tm][r] + bias;
        outv[tm][r] = o;
        int row = tm*16 + lg*4 + r;
        int byte = (row*192 + col*2) ^ ((row&7)<<4);
        *(ushort*)((char*)sMIH + byte) = f2bf(o);
      }
    }
  }
  __syncthreads();

  // ---- tension + block softmax stats (wave 0; 64 lanes <-> 64 rows)
  if (w == 0){
    int row = lane;
    float s = 0.f;
    #pragma unroll
    for (int c8=0; c8<8; c8++){
      int byte = (row*192 + c8*16) ^ ((row&7)<<4);
      bf16x8 v = lds_ld8(sMIH, byte);
      #pragma unroll
      for (int e2=0;e2<8;e2++){ float f = bf2f((unsigned short)v[e2]); s += f*f; }
    }
    float t = s * (1.0f/64.0f);
    { int byte = (row*192 + 128) ^ ((row&7)<<4);
      *(ushort*)((char*)sMIH + byte) = f2bf(t); }   // mem_in[64] = tension
    bool valid = row < nvalid;
    float m2 = valid ? t : -1.f;
    #pragma unroll
    for (int off=1; off<64; off<<=1) m2 = fmaxf(m2, __shfl_xor(m2, off));
    float e  = valid ? __expf(t - m2) : 0.f;
    float st = valid ? t : 0.f;
    float se = e, ss = st;
    #pragma unroll
    for (int off=1; off<64; off<<=1){ se += __shfl_xor(se, off); ss += __shfl_xor(ss, off); }
    sE[row] = e;
    if (lane == 0){
      float* rec = recs + (size_t)blockIdx.x*66;
      rec[0] = m2; rec[1] = se;
      atomicMax(tmax_u, __float_as_uint(m2));   // t >= 0
      atomicAdd(tsum, ss);
    }
  }
  __syncthreads();

  // ---- block-local softmax numerator (from registers)
  {
    float np = 0.f;
    #pragma unroll
    for (int tm=0;tm<4;tm++)
      #pragma unroll
      for (int r=0;r<4;r++){
        int row = tm*16 + lg*4 + r;
        np += sE[row] * outv[tm][r];
      }
    np += __shfl_xor(np, 16);
    np += __shfl_xor(np, 32);
    if (lg == 0) recs[(size_t)blockIdx.x*66 + 2 + jo2 + l15] = np;
  }

  // ---- GRU: wave w -> hidden cols [w*32, w*32+32)
  {
    int jo3 = w*32;
    f32x4 rr[4][2], zz[4][2], acci[4][2], acch[4][2];
    // r gate
    {
      f32x4 acc[4][2];
      #pragma unroll
      for (int tm=0;tm<4;tm++){ acc[tm][0]=(f32x4)0.f; acc[tm][1]=(f32x4)0.f; }
      gate_accum<true,true>(acc, sMIH, sH, Wgi, Whhb, 0, jo3, l15, lg);
      #pragma unroll
      for (int tn=0;tn<2;tn++){
        float b = brz[jo3 + tn*16 + l15];
        #pragma unroll
        for (int tm=0;tm<4;tm++)
          #pragma unroll
          for (int r=0;r<4;r++) rr[tm][tn][r] = sigmoidf_(acc[tm][tn][r] + b);
      }
    }
    // z gate
    {
      f32x4 acc[4][2];
      #pragma unroll
      for (int tm=0;tm<4;tm++){ acc[tm][0]=(f32x4)0.f; acc[tm][1]=(f32x4)0.f; }
      gate_accum<true,true>(acc, sMIH, sH, Wgi, Whhb, 128, jo3, l15, lg);
      #pragma unroll
      for (int tn=0;tn<2;tn++){
        float b = brz[128 + jo3 + tn*16 + l15];
        #pragma unroll
        for (int tm=0;tm<4;tm++)
          #pragma unroll
          for (int r=0;r<4;r++) zz[tm][tn][r] = sigmoidf_(acc[tm][tn][r] + b);
      }
    }
    // inn (mem only) and hn (h only)
    #pragma unroll
    for (int tm=0;tm<4;tm++){ acci[tm][0]=(f32x4)0.f; acci[tm][1]=(f32x4)0.f;
                              acch[tm][0]=(f32x4)0.f; acch[tm][1]=(f32x4)0.f; }
    gate_accum<true,false>(acci, sMIH, sH, Wgi, Whhb, 256, jo3, l15, lg);
    gate_accum<false,true>(acch, sMIH, sH, Wgi, Whhb, 256, jo3, l15, lg);
    // combine -> sNH (aliases sV1 region; sV1 is dead now)
    #pragma unroll
    for (int tn=0;tn<2;tn++){
      int col = jo3 + tn*16 + l15;
      float bi = bih[256+col], bh = bhh[256+col];
      #pragma unroll
      for (int tm=0;tm<4;tm++){
        #pragma unroll
        for (int r=0;r<4;r++){
          int row = tm*16 + lg*4 + r;
          float rv = rr[tm][tn][r], zv = zz[tm][tn][r];
          float nnv = tanhf(acci[tm][tn][r] + bi + rv*(acch[tm][tn][r] + bh));
          int hb = (row*256 + col*2) ^ ((row&7)<<4);
          float hv = bf2f(*(const ushort*)((const char*)sH + hb));
          sNH[row*128 + col] = (1.f - zv)*nnv + zv*hv;
        }
      }
    }
  }
  __syncthreads();

  // ---- scatter new_h (pre-faction) + faction column sums
  for (int e = tid; e < TMC*128; e += 256){
    int m = e >> 7, j = e & 127;
    if (m < nvalid) nh[(size_t)sIdx[m]*128 + j] = sNH[m*128 + j];
  }
  if (tid < 128){
    int j = tid;
    float s = 0.f; int fprev = -1;
    for (int m=0; m<nvalid; m++){
      int gi2 = base + m;
      int f = (gi2 < nffs) ? (gi2 / fs) : -1;
      if (f != fprev){
        if (fprev >= 0) atomicAdd(&facsum[fprev*128+j], s);
        s = 0.f; fprev = f;
      }
      if (f >= 0) s += sNH[m*128 + j];
    }
    if (fprev >= 0) atomicAdd(&facsum[fprev*128+j], s);
  }
}

// ---------- combine per-block softmax records ----------
__global__ void k_comb1(const float* __restrict__ recs, int nrec,
                        const unsigned* __restrict__ tmax_u,
                        float* __restrict__ num, float* __restrict__ S){
  int tid = threadIdx.x;
  int c = tid & 63, rg = tid >> 6;
  float M = __uint_as_float(*tmax_u);
  float acc = 0.f, sacc = 0.f;
  for (int r = blockIdx.x*4 + rg; r < nrec; r += gridDim.x*4){
    const float* rec = recs + (size_t)r*66;
    float e = __expf(rec[0] - M);
    acc += e * rec[2+c];
    if (c == 0) sacc += e * rec[1];
  }
  __shared__ float sn[4][64];
  __shared__ float ss[4];
  sn[rg][c] = acc;
  if (c == 0) ss[rg] = sacc;
  __syncthreads();
  if (tid < 64) atomicAdd(&num[tid], sn[0][tid]+sn[1][tid]+sn[2][tid]+sn[3][tid]);
  if (tid == 64) atomicAdd(S, ss[0]+ss[1]+ss[2]+ss[3]);
}

// ---------- finalize combined / mean_tension / faction means ----------
__global__ void k_final(const float* __restrict__ num, const float* __restrict__ S,
                        const float* __restrict__ tsum, const float* __restrict__ facsum,
                        float* __restrict__ out, float* __restrict__ go, float* __restrict__ fmn,
                        int n, int n_f, int fs){
  int tid = threadIdx.x;
  if (tid < 64) out[tid] = num[tid] / *S;
  else if (tid == 64) out[64] = *tsum / (float)n;
  if (tid >= 128 && n_f >= 2){
    int j = tid - 128;
    float s = 0.f;
    for (int f=0; f<n_f; f++){
      float v = facsum[f*128+j];
      s += v;
      fmn[f*128+j] = v / (float)fs;
    }
    go[j] = s / (float)(n_f*fs);
  }
}

// ---------- copy non-alive rows into new_hiddens ----------
__global__ void k_copy(const float* __restrict__ hid, const unsigned* __restrict__ flags,
                       float* __restrict__ nh, int total4){
  int stride = gridDim.x*blockDim.x;
  for (int i = blockIdx.x*blockDim.x + threadIdx.x; i < total4; i += stride){
    int e = i*4;
    if (!flags[e >> 7]){
      float4 v = *(const float4*)(hid + e);
      nh[e] = v.x; nh[e+1] = v.y; nh[e+2] = v.z; nh[e+3] = v.w;   // nh only 4B-aligned (d_out+65)
    }
  }
}

// ---------- in-place faction sync + debate on alive rows ----------
__global__ void k_faction(const int* __restrict__ alive, const float* __restrict__ fmn,
                          const float* __restrict__ go, const int* __restrict__ step_p,
                          float* __restrict__ nh, int nffs, int fs, int dc){
  int stride = gridDim.x*blockDim.x;
  int total = nffs*128;
  bool debate = (*step_p > 5);
  for (int e = blockIdx.x*blockDim.x + threadIdx.x; e < total; e += stride){
    int i = e >> 7, j = e & 127;
    int a = alive[i];
    size_t off = (size_t)a*128 + j;
    float v = nh[off];
    int f = i / fs;
    v = 0.85f*v + 0.15f*fmn[f*128+j];
    if (debate && (i - f*fs) < dc) v = 0.85f*v + 0.15f*go[j];
    nh[off] = v;
  }
}

extern "C" void kernel_launch(void* const* d_in, const int* in_sizes, int n_in,
                              void* d_out, int out_size, void* d_ws, size_t ws_size,
                              hipStream_t stream){
  const float* x    = (const float*)d_in[0];
  const float* hid  = (const float*)d_in[1];
  const float* Wa1  = (const float*)d_in[2];
  const float* ba1  = (const float*)d_in[3];
  const float* Wa2  = (const float*)d_in[4];
  const float* ba2  = (const float*)d_in[5];
  const float* Wg1  = (const float*)d_in[6];
  const float* bg1  = (const float*)d_in[7];
  const float* Wg2  = (const float*)d_in[8];
  const float* bg2  = (const float*)d_in[9];
  const float* Wih  = (const float*)d_in[10];
  const float* Whh  = (const float*)d_in[11];
  const float* bih  = (const float*)d_in[12];
  const float* bhh  = (const float*)d_in[13];
  const int*   alive= (const int*)d_in[14];
  const int*   step = (const int*)d_in[15];

  int n = in_sizes[14];
  int n_cells = in_sizes[1] / 128;
  int n_f = (n/2 < 8) ? n/2 : 8;
  int fs   = (n_f >= 2) ? n / n_f : 0;
  int nffs = (n_f >= 2) ? n_f * fs : 0;
  int dc   = (fs/4 > 1) ? fs/4 : 1;
  int nblocks = (n + TMC - 1) / TMC;

  float* out = (float*)d_out;
  float* nh  = out + 65;          // new_hiddens region (4B-aligned only!)
  float* ws  = (float*)d_ws;

  float* xab   = ws + 0;          // 256
  float* b2d   = ws + 256;        // 64
  float* brz   = ws + 320;        // 256
  float* facs  = ws + 576;        // 1024
  float* num   = ws + 1600;       // 64
  float* Ssum  = ws + 1664;       // 1
  float* tsum  = ws + 1665;       // 1
  unsigned* tmax_u = (unsigned*)(ws + 1666);  // 1 (+1 pad)
  float* go    = ws + 1668;       // 128
  float* fmn   = ws + 1796;       // 1024
  float* recs  = ws + 2820;       // nblocks*66
  int recs_end = 2820 + ((nblocks*66 + 3) & ~3);
  unsigned* flags = (unsigned*)(ws + recs_end);          // n_cells
  int woff = recs_end + n_cells;
  woff = (woff + 3) & ~3;
  ushort* W1p  = (ushort*)(ws + woff);                   // 256*128 bf16 = 16384 f
  ushort* W2p  = (ushort*)(ws + woff + 16384);           // 128*128 bf16 = 8192 f
  ushort* Wgi  = (ushort*)(ws + woff + 24576);           // 384*96  bf16 = 18432 f
  ushort* Whhb = (ushort*)(ws + woff + 43008);           // 384*128 bf16 = 24576 f

  // zero atomic accumulators (facs..tmax+pad) and flags
  hipMemsetAsync(ws + 576, 0, 1092*sizeof(float), stream);
  hipMemsetAsync(flags, 0, (size_t)n_cells*sizeof(unsigned), stream);

  k_pre<<<1,256,0,stream>>>(x, Wa1, ba1, Wg1, bg1, ba2, bg2, bih, bhh, xab, b2d, brz);
  k_pack<<<256,256,0,stream>>>(Wa1, Wg1, Wa2, Wg2, Wih, Whh, W1p, W2p, Wgi, Whhb);
  k_mark<<<(n+255)/256,256,0,stream>>>(alive, flags, n);
  k_main<<<nblocks,256,0,stream>>>(hid, alive, W1p, W2p, Wgi, Whhb, xab, b2d, brz,
                                   bih, bhh, nh, facs, recs, tmax_u, tsum,
                                   n, fs, nffs);
  k_comb1<<<64,256,0,stream>>>(recs, nblocks, tmax_u, num, Ssum);
  k_final<<<1,256,0,stream>>>(num, Ssum, tsum, facs, out, go, fmn, n, n_f, fs);
  k_copy<<<2048,256,0,stream>>>(hid, flags, nh, n_cells*128/4);
  if (n_f >= 2)
    k_faction<<<2048,256,0,stream>>>(alive, fmn, go, step, nh, nffs, fs, dc);
}

// Round 3
// 246.506 us; speedup vs baseline: 2.5090x; 1.0455x over previous
//
#include <hip/hip_runtime.h>
#include <math.h>

#define TMC 64   // cells per k_main block

typedef __attribute__((ext_vector_type(4))) float f32x4;
typedef __attribute__((ext_vector_type(8))) short bf16x8;

#define MFMA16(a,b,c) __builtin_amdgcn_mfma_f32_16x16x32_bf16((a),(b),(c),0,0,0)

__device__ __forceinline__ float sigmoidf_(float x){ return 1.0f/(1.0f + __expf(-x)); }
__device__ __forceinline__ float tanhf_(float x){
  float e = __expf(2.0f*x);
  return 1.0f - 2.0f/(e + 1.0f);
}

__device__ __forceinline__ unsigned short f2bf(float f){
  unsigned u = __float_as_uint(f);
  unsigned r = (u + 0x7FFFu + ((u>>16)&1u)) >> 16;
  return (unsigned short)r;
}
__device__ __forceinline__ unsigned pack2(float a, float b){
  return (unsigned)f2bf(a) | ((unsigned)f2bf(b)<<16);
}
__device__ __forceinline__ float bf2f(unsigned short u){ return __uint_as_float(((unsigned)u)<<16); }

__device__ __forceinline__ bf16x8 lds_ld8(const ushort* base, int byte){
  return *reinterpret_cast<const bf16x8*>(reinterpret_cast<const char*>(base) + byte);
}

// ---------- precompute: x-part of layer1 + combined biases (f32) ----------
__global__ void k_pre(const float* __restrict__ x,
                      const float* __restrict__ Wa1, const float* __restrict__ ba1,
                      const float* __restrict__ Wg1, const float* __restrict__ bg1,
                      const float* __restrict__ ba2, const float* __restrict__ bg2,
                      const float* __restrict__ bih, const float* __restrict__ bhh,
                      float* __restrict__ xab, float* __restrict__ b2d, float* __restrict__ brz){
  __shared__ float sx[64];
  int tid = threadIdx.x;
  if (tid < 64) sx[tid] = x[tid];
  __syncthreads();
  if (tid < 128){
    const float* w = Wa1 + tid*192;
    float s = ba1[tid];
    #pragma unroll
    for (int i=0;i<64;i++) s += w[i]*sx[i];
    xab[tid] = s;
  } else {
    int j = tid-128;
    const float* w = Wg1 + j*192;
    float s = bg1[j];
    #pragma unroll
    for (int i=0;i<64;i++) s += w[i]*sx[i];
    xab[tid] = s;
  }
  if (tid < 64) b2d[tid] = ba2[tid] - bg2[tid];
  brz[tid] = bih[tid] + bhh[tid];
}

// ---------- pack weights to bf16 fragment-contiguous layout ----------
// frag layout: elem(((nt*KS + ks)*64 + lane)*8 + e) = W[nt*16 + (lane&15)][ks*32 + (lane>>4)*8 + e]
__global__ void k_pack(const float* __restrict__ Wa1, const float* __restrict__ Wg1,
                       const float* __restrict__ Wa2, const float* __restrict__ Wg2,
                       const float* __restrict__ Wih, const float* __restrict__ Whh,
                       ushort* __restrict__ W1f, ushort* __restrict__ W2f,
                       ushort* __restrict__ Wgf, ushort* __restrict__ Whf,
                       float* __restrict__ w64){
  int stride = gridDim.x*blockDim.x;
  int t0 = blockIdx.x*blockDim.x + threadIdx.x;
  for (int i=t0; i<256*128; i+=stride){
    int e=i&7, lane=(i>>3)&63, ks=(i>>9)&3, nt=i>>11;
    int r = nt*16 + (lane&15), k = ks*32 + (lane>>4)*8 + e;
    float v = (r<128) ? Wa1[r*192+64+k] : Wg1[(r-128)*192+64+k];
    W1f[i] = f2bf(v);
  }
  for (int i=t0; i<128*128; i+=stride){
    int e=i&7, lane=(i>>3)&63, ks=(i>>9)&3, nt=i>>11;
    int r = nt*16 + (lane&15), k = ks*32 + (lane>>4)*8 + e;
    float v = (r<64) ? Wa2[r*128+k] : Wg2[(r-64)*128+k];
    W2f[i] = f2bf(v);
  }
  for (int i=t0; i<384*64; i+=stride){
    int e=i&7, lane=(i>>3)&63, ks=(i>>9)&1, nt=i>>10;
    int r = nt*16 + (lane&15), k = ks*32 + (lane>>4)*8 + e;
    Wgf[i] = f2bf(Wih[r*65+k]);
  }
  for (int i=t0; i<384*128; i+=stride){
    int e=i&7, lane=(i>>3)&63, ks=(i>>9)&3, nt=i>>11;
    int r = nt*16 + (lane&15), k = ks*32 + (lane>>4)*8 + e;
    Whf[i] = f2bf(Whh[r*128+k]);
  }
  for (int i=t0; i<384; i+=stride) w64[i] = Wih[i*65+64];
}

__global__ void k_mark(const int* __restrict__ alive, unsigned* __restrict__ flags, int n){
  int i = blockIdx.x*blockDim.x + threadIdx.x;
  if (i < n) flags[alive[i]] = 1u;
}

// GRU gate GEMM accumulate into acc[4 M-tiles][2 N-tiles]
template<bool DOMEM, bool DOH>
__device__ __forceinline__ void gru_accum(f32x4 (&acc)[4][2],
    const ushort* sMIH, const ushort* sH,
    const ushort* __restrict__ Wgf, const ushort* __restrict__ Whf,
    int ntbase, int lane, int l15, int lg)
{
  if (DOMEM){
    #pragma unroll
    for (int ks=0; ks<2; ks++){
      bf16x8 a[4], b[2];
      #pragma unroll
      for (int tm=0; tm<4; tm++){
        int row = tm*16 + l15;
        a[tm] = lds_ld8(sMIH, (row*128 + ks*64 + lg*16) ^ ((row&7)<<4));
      }
      #pragma unroll
      for (int tn=0; tn<2; tn++)
        b[tn] = *(const bf16x8*)(Wgf + ((((ntbase+tn)*2 + ks)*64 + lane)<<3));
      #pragma unroll
      for (int tm=0; tm<4; tm++)
        #pragma unroll
        for (int tn=0; tn<2; tn++)
          acc[tm][tn] = MFMA16(a[tm], b[tn], acc[tm][tn]);
    }
  }
  if (DOH){
    #pragma unroll
    for (int ks=0; ks<4; ks++){
      bf16x8 a[4], b[2];
      #pragma unroll
      for (int tm=0; tm<4; tm++){
        int row = tm*16 + l15;
        a[tm] = lds_ld8(sH, (row*256 + ks*64 + lg*16) ^ ((row&7)<<4));
      }
      #pragma unroll
      for (int tn=0; tn<2; tn++)
        b[tn] = *(const bf16x8*)(Whf + ((((ntbase+tn)*4 + ks)*64 + lane)<<3));
      #pragma unroll
      for (int tm=0; tm<4; tm++)
        #pragma unroll
        for (int tn=0; tn<2; tn++)
          acc[tm][tn] = MFMA16(a[tm], b[tn], acc[tm][tn]);
    }
  }
}

// ---------- main MFMA kernel: 64 cells / block, 4 waves, 3 blocks/CU ----------
__global__ __launch_bounds__(256,3) void k_main(
    const float* __restrict__ hiddens, const int* __restrict__ alive,
    const ushort* __restrict__ W1f, const ushort* __restrict__ W2f,
    const ushort* __restrict__ Wgf, const ushort* __restrict__ Whf,
    const float* __restrict__ w64,
    const float* __restrict__ xab, const float* __restrict__ b2d,
    const float* __restrict__ brz,
    const float* __restrict__ bih, const float* __restrict__ bhh,
    float* __restrict__ nh, float* __restrict__ facsum,
    float* __restrict__ recs, unsigned* __restrict__ tmax_u, float* __restrict__ tsum,
    int n, int fs, int nffs)
{
  __shared__ ushort sH[64*128];                   // 16 KB bf16, swizzled, stride 256B
  __shared__ __align__(16) ushort arena[64*256];  // 32 KB: sV1 (stride 512B); sMIH aliases first 8KB after GEMM2
  __shared__ float sTS[4][64];
  __shared__ float sT[64];
  __shared__ float sE[64];
  __shared__ int   sIdx[TMC];

  ushort* sV1  = arena;
  ushort* sMIH = arena;   // [64][64] bf16, swizzled, stride 128B (after GEMM2 barrier)

  int tid = threadIdx.x;
  int lane = tid & 63;
  int w = tid >> 6;
  int l15 = lane & 15;
  int lg  = lane >> 4;

  int base = blockIdx.x * TMC;
  int nvalid = n - base; if (nvalid > TMC) nvalid = TMC;

  if (tid < TMC){
    int t2 = tid < nvalid ? tid : (nvalid-1);
    sIdx[tid] = alive[base + t2];
  }
  __syncthreads();

  // ---- stage h -> bf16 LDS (swizzled)
  {
    int m = tid >> 2, c0 = (tid & 3) * 32;
    const float* src = hiddens + (size_t)sIdx[m]*128 + c0;
    #pragma unroll
    for (int j=0; j<32; j+=8){
      float4 v0 = *(const float4*)(src + j);
      float4 v1 = *(const float4*)(src + j + 4);
      uint4 pk;
      pk.x = pack2(v0.x, v0.y); pk.y = pack2(v0.z, v0.w);
      pk.z = pack2(v1.x, v1.y); pk.w = pack2(v1.z, v1.w);
      int byte = (m*256 + (c0 + j)*2) ^ ((m&7)<<4);
      *reinterpret_cast<uint4*>(reinterpret_cast<char*>(sH) + byte) = pk;
    }
  }
  __syncthreads();

  // ---- GEMM1: v1 = relu(h @ W1h^T + xab); wave w -> cols [w*64, w*64+64)
  {
    int c0 = w*64;
    f32x4 acc[4][4];
    #pragma unroll
    for (int tm=0;tm<4;tm++)
      #pragma unroll
      for (int tn=0;tn<4;tn++) acc[tm][tn] = (f32x4)0.f;
    #pragma unroll
    for (int ks=0; ks<4; ks++){
      bf16x8 a[4], b[4];
      #pragma unroll
      for (int tm=0;tm<4;tm++){
        int row = tm*16 + l15;
        a[tm] = lds_ld8(sH, (row*256 + ks*64 + lg*16) ^ ((row&7)<<4));
      }
      #pragma unroll
      for (int tn=0;tn<4;tn++)
        b[tn] = *(const bf16x8*)(W1f + ((((w*4+tn)*4 + ks)*64 + lane)<<3));
      #pragma unroll
      for (int tm=0;tm<4;tm++)
        #pragma unroll
        for (int tn=0;tn<4;tn++)
          acc[tm][tn] = MFMA16(a[tm], b[tn], acc[tm][tn]);
    }
    #pragma unroll
    for (int tn=0;tn<4;tn++){
      int col = c0 + tn*16 + l15;
      float bias = xab[col];
      #pragma unroll
      for (int tm=0;tm<4;tm++){
        #pragma unroll
        for (int r=0;r<4;r++){
          int row = tm*16 + lg*4 + r;
          float v = fmaxf(acc[tm][tn][r] + bias, 0.f);
          int byte = (row*512 + col*2) ^ ((row&7)<<4);
          *(ushort*)((char*)sV1 + byte) = f2bf(v);
        }
      }
    }
  }
  __syncthreads();

  // ---- GEMM2: out = a - g; wave w -> out cols [w*16, w*16+16)
  int jo2 = w*16;
  float outv[4][4];
  {
    f32x4 accA[4], accG[4];
    #pragma unroll
    for (int tm=0;tm<4;tm++){ accA[tm]=(f32x4)0.f; accG[tm]=(f32x4)0.f; }
    #pragma unroll
    for (int ks=0; ks<4; ks++){
      bf16x8 aA[4], aG[4], bA, bG;
      #pragma unroll
      for (int tm=0;tm<4;tm++){
        int row = tm*16 + l15;
        aA[tm] = lds_ld8(sV1, (row*512 + ks*64 + lg*16) ^ ((row&7)<<4));
        aG[tm] = lds_ld8(sV1, (row*512 + 256 + ks*64 + lg*16) ^ ((row&7)<<4));
      }
      bA = *(const bf16x8*)(W2f + (((w*4 + ks)*64 + lane)<<3));
      bG = *(const bf16x8*)(W2f + ((((4+w)*4 + ks)*64 + lane)<<3));
      #pragma unroll
      for (int tm=0;tm<4;tm++){
        accA[tm] = MFMA16(aA[tm], bA, accA[tm]);
        accG[tm] = MFMA16(aG[tm], bG, accG[tm]);
      }
    }
    int col = jo2 + l15;
    float bias = b2d[col];
    #pragma unroll
    for (int tm=0;tm<4;tm++)
      #pragma unroll
      for (int r=0;r<4;r++)
        outv[tm][r] = accA[tm][r] - accG[tm][r] + bias;
  }
  __syncthreads();   // all sV1 reads done; arena reusable as sMIH

  // ---- epilogue: write out (bf16, K=64 layout) + per-wave tension partials
  {
    int col = jo2 + l15;
    float p[4][4];
    #pragma unroll
    for (int tm=0;tm<4;tm++){
      #pragma unroll
      for (int r=0;r<4;r++){
        int row = tm*16 + lg*4 + r;
        float o = outv[tm][r];
        int byte = (row*128 + col*2) ^ ((row&7)<<4);
        *(ushort*)((char*)sMIH + byte) = f2bf(o);
        p[tm][r] = o*o;
      }
    }
    #pragma unroll
    for (int off=1; off<16; off<<=1)
      #pragma unroll
      for (int tm=0;tm<4;tm++)
        #pragma unroll
        for (int r=0;r<4;r++) p[tm][r] += __shfl_xor(p[tm][r], off);
    if (l15 == 0){
      #pragma unroll
      for (int tm=0;tm<4;tm++)
        #pragma unroll
        for (int r=0;r<4;r++) sTS[w][tm*16 + lg*4 + r] = p[tm][r];
    }
  }
  __syncthreads();

  // ---- tension stats (wave 0; 64 lanes <-> 64 rows)
  if (w == 0){
    int row = lane;
    float t = (sTS[0][row] + sTS[1][row] + sTS[2][row] + sTS[3][row]) * (1.0f/64.0f);
    sT[row] = t;
    bool valid = row < nvalid;
    float m2 = valid ? t : -1.f;
    #pragma unroll
    for (int off=1; off<64; off<<=1) m2 = fmaxf(m2, __shfl_xor(m2, off));
    float e  = valid ? __expf(t - m2) : 0.f;
    float st = valid ? t : 0.f;
    float se = e, ss = st;
    #pragma unroll
    for (int off=1; off<64; off<<=1){ se += __shfl_xor(se, off); ss += __shfl_xor(ss, off); }
    sE[row] = e;
    if (lane == 0){
      float* rec = recs + (size_t)blockIdx.x*66;
      rec[0] = m2; rec[1] = se;
      atomicMax(tmax_u, __float_as_uint(m2));   // t >= 0
      atomicAdd(tsum, ss);
    }
  }
  __syncthreads();

  // ---- block-local softmax numerator (from registers)
  {
    float np = 0.f;
    #pragma unroll
    for (int tm=0;tm<4;tm++)
      #pragma unroll
      for (int r=0;r<4;r++)
        np += sE[tm*16 + lg*4 + r] * outv[tm][r];
    np += __shfl_xor(np, 16);
    np += __shfl_xor(np, 32);
    if (lg == 0) recs[(size_t)blockIdx.x*66 + 2 + jo2 + l15] = np;
  }

  // ---- load tension per-row into regs
  float t16v[4][4];
  #pragma unroll
  for (int tm=0;tm<4;tm++)
    #pragma unroll
    for (int r=0;r<4;r++) t16v[tm][r] = sT[tm*16 + lg*4 + r];

  // ---- GRU: wave w -> hidden cols [w*32, w*32+32)
  {
    int jo3 = w*32;
    int ntb = w*2;
    // hn pre-activation (h part of candidate)
    f32x4 hnA[4][2];
    #pragma unroll
    for (int tm=0;tm<4;tm++){ hnA[tm][0]=(f32x4)0.f; hnA[tm][1]=(f32x4)0.f; }
    gru_accum<false,true>(hnA, sMIH, sH, Wgf, Whf, 16 + ntb, lane, l15, lg);
    // r gate -> fold into hnA = r*(hn + bhh_n)
    {
      f32x4 gA[4][2];
      #pragma unroll
      for (int tm=0;tm<4;tm++){ gA[tm][0]=(f32x4)0.f; gA[tm][1]=(f32x4)0.f; }
      gru_accum<true,true>(gA, sMIH, sH, Wgf, Whf, 0 + ntb, lane, l15, lg);
      #pragma unroll
      for (int tn=0;tn<2;tn++){
        int col = jo3 + tn*16 + l15;
        float b = brz[col], wv = w64[col], bhn = bhh[256+col];
        #pragma unroll
        for (int tm=0;tm<4;tm++)
          #pragma unroll
          for (int r=0;r<4;r++){
            float rr = sigmoidf_(gA[tm][tn][r] + b + t16v[tm][r]*wv);
            hnA[tm][tn][r] = rr * (hnA[tm][tn][r] + bhn);
          }
      }
    }
    // z gate
    f32x4 zA[4][2];
    #pragma unroll
    for (int tm=0;tm<4;tm++){ zA[tm][0]=(f32x4)0.f; zA[tm][1]=(f32x4)0.f; }
    gru_accum<true,true>(zA, sMIH, sH, Wgf, Whf, 8 + ntb, lane, l15, lg);
    #pragma unroll
    for (int tn=0;tn<2;tn++){
      int col = jo3 + tn*16 + l15;
      float b = brz[128+col], wv = w64[128+col];
      #pragma unroll
      for (int tm=0;tm<4;tm++)
        #pragma unroll
        for (int r=0;r<4;r++)
          zA[tm][tn][r] = sigmoidf_(zA[tm][tn][r] + b + t16v[tm][r]*wv);
    }
    // inn (mem part of candidate)
    f32x4 iA[4][2];
    #pragma unroll
    for (int tm=0;tm<4;tm++){ iA[tm][0]=(f32x4)0.f; iA[tm][1]=(f32x4)0.f; }
    gru_accum<true,false>(iA, sMIH, sH, Wgf, Whf, 16 + ntb, lane, l15, lg);

    // ---- final combine + direct scatter + faction sums
    int lastrow = nvalid;
    if (base + lastrow > nffs) lastrow = nffs - base;
    int f0 = (fs > 0 && base < nffs) ? base / fs : 0;
    bool onefac = (lastrow <= 0) || ((base + lastrow - 1) / fs == f0);

    #pragma unroll
    for (int tn=0;tn<2;tn++){
      int col = jo3 + tn*16 + l15;
      float bi = bih[256+col], wv = w64[256+col];
      float fsum = 0.f;
      #pragma unroll
      for (int tm=0;tm<4;tm++){
        #pragma unroll
        for (int r=0;r<4;r++){
          int row = tm*16 + lg*4 + r;
          float nnv = tanhf_(iA[tm][tn][r] + bi + t16v[tm][r]*wv + hnA[tm][tn][r]);
          int hb = (row*256 + col*2) ^ ((row&7)<<4);
          float hv = bf2f(*(const ushort*)((const char*)sH + hb));
          float zv = zA[tm][tn][r];
          float v = (1.f - zv)*nnv + zv*hv;
          if (row < nvalid) nh[(size_t)sIdx[row]*128 + col] = v;
          if (onefac){
            if (row < lastrow) fsum += v;
          } else if (row < lastrow){
            atomicAdd(&facsum[((base+row)/fs)*128 + col], v);
          }
        }
      }
      if (onefac && lastrow > 0){
        fsum += __shfl_xor(fsum, 16);
        fsum += __shfl_xor(fsum, 32);
        if (lg == 0) atomicAdd(&facsum[f0*128 + col], fsum);
      }
    }
  }
}

// ---------- combine per-block softmax records ----------
__global__ void k_comb1(const float* __restrict__ recs, int nrec,
                        const unsigned* __restrict__ tmax_u,
                        float* __restrict__ num, float* __restrict__ S){
  int tid = threadIdx.x;
  int c = tid & 63, rg = tid >> 6;
  float M = __uint_as_float(*tmax_u);
  float acc = 0.f, sacc = 0.f;
  for (int r = blockIdx.x*4 + rg; r < nrec; r += gridDim.x*4){
    const float* rec = recs + (size_t)r*66;
    float e = __expf(rec[0] - M);
    acc += e * rec[2+c];
    if (c == 0) sacc += e * rec[1];
  }
  __shared__ float sn[4][64];
  __shared__ float ss[4];
  sn[rg][c] = acc;
  if (c == 0) ss[rg] = sacc;
  __syncthreads();
  if (tid < 64) atomicAdd(&num[tid], sn[0][tid]+sn[1][tid]+sn[2][tid]+sn[3][tid]);
  if (tid == 64) atomicAdd(S, ss[0]+ss[1]+ss[2]+ss[3]);
}

// ---------- finalize combined / mean_tension / faction means ----------
__global__ void k_final(const float* __restrict__ num, const float* __restrict__ S,
                        const float* __restrict__ tsum, const float* __restrict__ facsum,
                        float* __restrict__ out, float* __restrict__ go, float* __restrict__ fmn,
                        int n, int n_f, int fs){
  int tid = threadIdx.x;
  if (tid < 64) out[tid] = num[tid] / *S;
  else if (tid == 64) out[64] = *tsum / (float)n;
  if (tid >= 128 && n_f >= 2){
    int j = tid - 128;
    float s = 0.f;
    for (int f=0; f<n_f; f++){
      float v = facsum[f*128+j];
      s += v;
      fmn[f*128+j] = v / (float)fs;
    }
    go[j] = s / (float)(n_f*fs);
  }
}

// ---------- copy non-alive rows into new_hiddens ----------
__global__ void k_copy(const float* __restrict__ hid, const unsigned* __restrict__ flags,
                       float* __restrict__ nh, int total4){
  int stride = gridDim.x*blockDim.x;
  for (int i = blockIdx.x*blockDim.x + threadIdx.x; i < total4; i += stride){
    int e = i*4;
    if (!flags[e >> 7]){
      float4 v = *(const float4*)(hid + e);
      nh[e] = v.x; nh[e+1] = v.y; nh[e+2] = v.z; nh[e+3] = v.w;   // nh only 4B-aligned (d_out+65)
    }
  }
}

// ---------- in-place faction sync + debate on alive rows ----------
__global__ void k_faction(const int* __restrict__ alive, const float* __restrict__ fmn,
                          const float* __restrict__ go, const int* __restrict__ step_p,
                          float* __restrict__ nh, int nffs, int fs, int dc){
  int stride = gridDim.x*blockDim.x;
  int total = nffs*128;
  bool debate = (*step_p > 5);
  for (int e = blockIdx.x*blockDim.x + threadIdx.x; e < total; e += stride){
    int i = e >> 7, j = e & 127;
    int a = alive[i];
    size_t off = (size_t)a*128 + j;
    float v = nh[off];
    int f = i / fs;
    v = 0.85f*v + 0.15f*fmn[f*128+j];
    if (debate && (i - f*fs) < dc) v = 0.85f*v + 0.15f*go[j];
    nh[off] = v;
  }
}

extern "C" void kernel_launch(void* const* d_in, const int* in_sizes, int n_in,
                              void* d_out, int out_size, void* d_ws, size_t ws_size,
                              hipStream_t stream){
  const float* x    = (const float*)d_in[0];
  const float* hid  = (const float*)d_in[1];
  const float* Wa1  = (const float*)d_in[2];
  const float* ba1  = (const float*)d_in[3];
  const float* Wa2  = (const float*)d_in[4];
  const float* ba2  = (const float*)d_in[5];
  const float* Wg1  = (const float*)d_in[6];
  const float* bg1  = (const float*)d_in[7];
  const float* Wg2  = (const float*)d_in[8];
  const float* bg2  = (const float*)d_in[9];
  const float* Wih  = (const float*)d_in[10];
  const float* Whh  = (const float*)d_in[11];
  const float* bih  = (const float*)d_in[12];
  const float* bhh  = (const float*)d_in[13];
  const int*   alive= (const int*)d_in[14];
  const int*   step = (const int*)d_in[15];

  int n = in_sizes[14];
  int n_cells = in_sizes[1] / 128;
  int n_f = (n/2 < 8) ? n/2 : 8;
  int fs   = (n_f >= 2) ? n / n_f : 0;
  int nffs = (n_f >= 2) ? n_f * fs : 0;
  int dc   = (fs/4 > 1) ? fs/4 : 1;
  int nblocks = (n + TMC - 1) / TMC;

  float* out = (float*)d_out;
  float* nh  = out + 65;          // new_hiddens region (4B-aligned only!)
  float* ws  = (float*)d_ws;

  float* xab   = ws + 0;          // 256
  float* b2d   = ws + 256;        // 64
  float* brz   = ws + 320;        // 256
  float* facs  = ws + 576;        // 1024
  float* num   = ws + 1600;       // 64
  float* Ssum  = ws + 1664;       // 1
  float* tsum  = ws + 1665;       // 1
  unsigned* tmax_u = (unsigned*)(ws + 1666);  // 1 (+1 pad)
  float* go    = ws + 1668;       // 128
  float* fmn   = ws + 1796;       // 1024
  float* w64   = ws + 2820;       // 384
  float* recs  = ws + 3204;       // nblocks*66
  int recs_end = 3204 + ((nblocks*66 + 3) & ~3);
  unsigned* flags = (unsigned*)(ws + recs_end);          // n_cells
  int woff = (recs_end + n_cells + 3) & ~3;
  ushort* W1f  = (ushort*)(ws + woff);                   // 256*128 bf16 = 16384 f
  ushort* W2f  = (ushort*)(ws + woff + 16384);           // 128*128 bf16 = 8192 f
  ushort* Wgf  = (ushort*)(ws + woff + 24576);           // 384*64  bf16 = 12288 f
  ushort* Whf  = (ushort*)(ws + woff + 36864);           // 384*128 bf16 = 24576 f

  // zero atomic accumulators (facs..tmax+pad) and flags
  hipMemsetAsync(ws + 576, 0, 1092*sizeof(float), stream);
  hipMemsetAsync(flags, 0, (size_t)n_cells*sizeof(unsigned), stream);

  k_pre<<<1,256,0,stream>>>(x, Wa1, ba1, Wg1, bg1, ba2, bg2, bih, bhh, xab, b2d, brz);
  k_pack<<<256,256,0,stream>>>(Wa1, Wg1, Wa2, Wg2, Wih, Whh, W1f, W2f, Wgf, Whf, w64);
  k_mark<<<(n+255)/256,256,0,stream>>>(alive, flags, n);
  k_copy<<<2048,256,0,stream>>>(hid, flags, nh, n_cells*128/4);
  k_main<<<nblocks,256,0,stream>>>(hid, alive, W1f, W2f, Wgf, Whf, w64, xab, b2d, brz,
                                   bih, bhh, nh, facs, recs, tmax_u, tsum,
                                   n, fs, nffs);
  k_comb1<<<64,256,0,stream>>>(recs, nblocks, tmax_u, num, Ssum);
  k_final<<<1,256,0,stream>>>(num, Ssum, tsum, facs, out, go, fmn, n, n_f, fs);
  if (n_f >= 2)
    k_faction<<<2048,256,0,stream>>>(alive, fmn, go, step, nh, nffs, fs, dc);
}